// Round 8
// baseline (117.635 us; speedup 1.0000x reference)
//
#include <hip/hip_runtime.h>

// ECConv: out = relu(concat(nf[:8192], mean_seg(relu(EF@We+be).reshape(E,64,64) @ h_src)) @ Wn + bn)
// Sizes: E=65536, N_SRC=32768, N_DST=8192, EDGE_IN=32, NODE_IN=64, HIDDEN=64
// R8: MLP (memory-level-parallelism) round. Evidence: R4/R6/R7 all 48-49us despite occupancy
//     22-45% and VALU cuts -> per-iteration B-frag L2-latency stall (1 load in flight, depth-2
//     cover < 250cyc). Fix: wave owns EDGE-group, loops all 4 ht -> 4 independent B-loads/iter
//     (8 in flight with dbuf), all 4 waves share the same Wp/bp stream (L1 temporal hits),
//     hvf ds_read prefetched. Same MFMA count/stores.
// Lessons: R2 fp32 device atomics memory-side (~50-85G dword/s floor). R4 serial scan 20us.
//     R5 forced VGPR=32 -> 92MB spill traffic; sequential dispatches don't add blocks/CU.
//     R6/R7: occupancy beyond ~2 waves/SIMD buys nothing here -> not TLP-limited.

typedef float f32x4 __attribute__((ext_vector_type(4)));
typedef float f32x2 __attribute__((ext_vector_type(2)));
typedef __bf16 bf16x8 __attribute__((ext_vector_type(8)));
typedef __bf16 bf16x4 __attribute__((ext_vector_type(4)));

#define E_TOT   65536
#define NDST    8192
#define EPW     72    // bf16 hs pad (atomic-fallback kernel)
#define EPF     68    // f32 hs pad (fast kernel)

// ---- prep: pack We (fp32 [32][4096]) -> MFMA-B fragment order bf16 + bias tiles ----
// Tile T = d0*4 + ht covers GEMM cols n = (ht*16 + c)*64 + d0, c=0..15.
// B frag for mfma_f32_16x16x32_bf16: lane l holds B[k=(l>>4)*8+j][col=l&15], j=0..7.
__global__ __launch_bounds__(256) void prep_kernel(
    const float* __restrict__ We, const float* __restrict__ be,
    __bf16* __restrict__ Wp, float* __restrict__ bp) {
  int tid = blockIdx.x * 256 + threadIdx.x;       // 16384 packers
  int T = tid >> 6, l = tid & 63;
  int d0 = T >> 2, ht = T & 3;
  int c = l & 15, kg = l >> 4;
  int ncol = (ht * 16 + c) * 64 + d0;
  bf16x8 v;
#pragma unroll
  for (int j = 0; j < 8; ++j) v[j] = (__bf16)We[(kg * 8 + j) * 4096 + ncol];
  *reinterpret_cast<bf16x8*>(Wp + tid * 8) = v;
  if (l < 16) bp[T * 16 + l] = be[(ht * 16 + l) * 64 + d0];
}

// ---- parallel exclusive scan over 8192 bins (one block, shfl + LDS) ----
__global__ __launch_bounds__(256) void scan_kernel(const int* __restrict__ cnt_i,
                                                   int* __restrict__ off,
                                                   int* __restrict__ cursor) {
  __shared__ int wsum[4];
  const int t = threadIdx.x;           // each thread owns 32 consecutive bins
  const int lane = t & 63, w = t >> 6;
  int vals[32];
  const int4* cp = (const int4*)(cnt_i + t * 32);
#pragma unroll
  for (int i = 0; i < 8; ++i) {
    int4 v = cp[i];
    vals[i * 4 + 0] = v.x; vals[i * 4 + 1] = v.y;
    vals[i * 4 + 2] = v.z; vals[i * 4 + 3] = v.w;
  }
  int loc[32];
  int s = 0;
#pragma unroll
  for (int i = 0; i < 32; ++i) { loc[i] = s; s += vals[i]; }
  int inc = s;
#pragma unroll
  for (int d = 1; d < 64; d <<= 1) {
    int n = __shfl_up(inc, d, 64);
    if (lane >= d) inc += n;
  }
  if (lane == 63) wsum[w] = inc;
  __syncthreads();
  int base = inc - s;
#pragma unroll
  for (int i = 0; i < 4; ++i)
    if (i < w) base += wsum[i];
#pragma unroll
  for (int i = 0; i < 32; ++i) {
    int v = base + loc[i];
    off[t * 32 + i] = v;
    cursor[t * 32 + i] = v;
  }
  if (t == 255) off[8192] = E_TOT;
}

// ---- fill: scatter edge ids into CSR order (int atomics on cursor) ----
__global__ void fill_kernel(const int* __restrict__ dst, int* __restrict__ cursor,
                            int* __restrict__ eid) {
  int e = blockIdx.x * 256 + threadIdx.x;
  int slot = atomicAdd(&cursor[dst[e]], 1);
  eid[slot] = e;
}

// ---- edge compute: m[e][h] = sum_d relu(ef[e]@We[:,h,d] + be[h,d]) * h_src[e][d] ----
// Block: 4 waves, 64 edges. Wave w owns EDGE-group w (16 edges, 1 A-frag) and computes all
// 4 ht quadrants per d0: 4 independent B-loads/iter, shared across waves (L1 temporal hits).
// Depth-2 named-reg dbuf on {4x B-frag, 4x bias, hvf}. Also does dst histogram.
__global__ __launch_bounds__(256, 4) void edge6_kernel(
    const float* __restrict__ nf, const float* __restrict__ ef,
    const int* __restrict__ src, const int* __restrict__ dst,
    const __bf16* __restrict__ Wp, const float* __restrict__ bp,
    float* __restrict__ m, int* __restrict__ cnt_i) {
  __shared__ float hs[64 * EPF];   // transposed f32 h_src: hs[d][e_local], 17.4 KB
  const int t = threadIdx.x;
  const int eblk = blockIdx.x << 6;

  // stage h_src transposed: thread t -> edge el=t&63, d-quarter q=t>>6 (16 d each)
  {
    const int el = t & 63, q = t >> 6;
    const int srow = src[eblk + el];
    const f32x4* nfr = (const f32x4*)(nf + (srow << 6) + (q << 4));
#pragma unroll
    for (int i = 0; i < 4; ++i) {
      f32x4 v = nfr[i];
      const int dbase = (q << 4) + i * 4;
      hs[(dbase + 0) * EPF + el] = v[0];
      hs[(dbase + 1) * EPF + el] = v[1];
      hs[(dbase + 2) * EPF + el] = v[2];
      hs[(dbase + 3) * EPF + el] = v[3];
    }
  }

  // fused dst histogram (feeds CSR for final; cnt_i pre-zeroed by memset)
  if (t < 64) atomicAdd(&cnt_i[dst[eblk + t]], 1);

  const int w = t >> 6, l = t & 63;
  const int c = l & 15, g = l >> 4;

  // ONE A fragment: this wave's 16 edges. lane holds A[row=c][k=g*8+j]
  bf16x8 afr;
  {
    const int e = eblk + (w << 4) + c;
    const f32x4* p = (const f32x4*)(ef + (e << 5) + (g << 3));
    f32x4 v0 = p[0], v1 = p[1];
    afr[0] = (__bf16)v0[0]; afr[1] = (__bf16)v0[1]; afr[2] = (__bf16)v0[2]; afr[3] = (__bf16)v0[3];
    afr[4] = (__bf16)v1[0]; afr[5] = (__bf16)v1[1]; afr[6] = (__bf16)v1[2]; afr[7] = (__bf16)v1[3];
  }

  const bf16x8* WpV = (const bf16x8*)Wp;

  // prologue: depth-2 B/bias prefetch (wave-shared addresses; 8 loads in flight)
  bf16x8 bA0 = WpV[(0 * 4 + 0) * 64 + l];
  bf16x8 bA1 = WpV[(0 * 4 + 1) * 64 + l];
  bf16x8 bA2 = WpV[(0 * 4 + 2) * 64 + l];
  bf16x8 bA3 = WpV[(0 * 4 + 3) * 64 + l];
  float  vA0 = bp[(0 * 4 + 0) * 16 + c];
  float  vA1 = bp[(0 * 4 + 1) * 16 + c];
  float  vA2 = bp[(0 * 4 + 2) * 16 + c];
  float  vA3 = bp[(0 * 4 + 3) * 16 + c];
  bf16x8 bB0 = WpV[(1 * 4 + 0) * 64 + l];
  bf16x8 bB1 = WpV[(1 * 4 + 1) * 64 + l];
  bf16x8 bB2 = WpV[(1 * 4 + 2) * 64 + l];
  bf16x8 bB3 = WpV[(1 * 4 + 3) * 64 + l];
  float  vB0 = bp[(1 * 4 + 0) * 16 + c];
  float  vB1 = bp[(1 * 4 + 1) * 16 + c];
  float  vB2 = bp[(1 * 4 + 2) * 16 + c];
  float  vB3 = bp[(1 * 4 + 3) * 16 + c];

  f32x2 accA[4], accB[4];   // per ht: rows (g*4+0, g*4+1) and (g*4+2, g*4+3)
#pragma unroll
  for (int i = 0; i < 4; ++i) {
    accA[i][0] = 0.f; accA[i][1] = 0.f;
    accB[i][0] = 0.f; accB[i][1] = 0.f;
  }

  __syncthreads();

  const int hoff = (w << 4) + (g << 2);     // this wave's hs row group
  f32x4 hvA = *(const f32x4*)&hs[0 * EPF + hoff];
  f32x4 hvB = *(const f32x4*)&hs[1 * EPF + hoff];

#define EDGE_SECTION(B0, B1, B2, B3, V0, V1, V2, V3, HV)                            \
  {                                                                                  \
    const f32x4 cb0 = {V0, V0, V0, V0};                                              \
    const f32x4 cb1 = {V1, V1, V1, V1};                                              \
    const f32x4 cb2 = {V2, V2, V2, V2};                                              \
    const f32x4 cb3 = {V3, V3, V3, V3};                                              \
    f32x4 t0 = __builtin_amdgcn_mfma_f32_16x16x32_bf16(afr, B0, cb0, 0, 0, 0);       \
    f32x4 t1 = __builtin_amdgcn_mfma_f32_16x16x32_bf16(afr, B1, cb1, 0, 0, 0);       \
    f32x4 t2 = __builtin_amdgcn_mfma_f32_16x16x32_bf16(afr, B2, cb2, 0, 0, 0);       \
    f32x4 t3 = __builtin_amdgcn_mfma_f32_16x16x32_bf16(afr, B3, cb3, 0, 0, 0);       \
    f32x2 hl = __builtin_shufflevector(HV, HV, 0, 1);                                \
    f32x2 hh = __builtin_shufflevector(HV, HV, 2, 3);                                \
    f32x2 p;                                                                         \
    p[0] = fmaxf(t0[0], 0.f); p[1] = fmaxf(t0[1], 0.f);                              \
    asm("v_pk_fma_f32 %0, %1, %2, %0" : "+v"(accA[0]) : "v"(p), "v"(hl));            \
    p[0] = fmaxf(t0[2], 0.f); p[1] = fmaxf(t0[3], 0.f);                              \
    asm("v_pk_fma_f32 %0, %1, %2, %0" : "+v"(accB[0]) : "v"(p), "v"(hh));            \
    p[0] = fmaxf(t1[0], 0.f); p[1] = fmaxf(t1[1], 0.f);                              \
    asm("v_pk_fma_f32 %0, %1, %2, %0" : "+v"(accA[1]) : "v"(p), "v"(hl));            \
    p[0] = fmaxf(t1[2], 0.f); p[1] = fmaxf(t1[3], 0.f);                              \
    asm("v_pk_fma_f32 %0, %1, %2, %0" : "+v"(accB[1]) : "v"(p), "v"(hh));            \
    p[0] = fmaxf(t2[0], 0.f); p[1] = fmaxf(t2[1], 0.f);                              \
    asm("v_pk_fma_f32 %0, %1, %2, %0" : "+v"(accA[2]) : "v"(p), "v"(hl));            \
    p[0] = fmaxf(t2[2], 0.f); p[1] = fmaxf(t2[3], 0.f);                              \
    asm("v_pk_fma_f32 %0, %1, %2, %0" : "+v"(accB[2]) : "v"(p), "v"(hh));            \
    p[0] = fmaxf(t3[0], 0.f); p[1] = fmaxf(t3[1], 0.f);                              \
    asm("v_pk_fma_f32 %0, %1, %2, %0" : "+v"(accA[3]) : "v"(p), "v"(hl));            \
    p[0] = fmaxf(t3[2], 0.f); p[1] = fmaxf(t3[3], 0.f);                              \
    asm("v_pk_fma_f32 %0, %1, %2, %0" : "+v"(accB[3]) : "v"(p), "v"(hh));            \
  }

  for (int d0 = 0; d0 < 64; d0 += 2) {
    // ---- even section: consume A set, prefetch A <- d0+2 ----
    {
      const bf16x8 u0 = bA0, u1 = bA1, u2 = bA2, u3 = bA3;
      const float  x0 = vA0, x1 = vA1, x2 = vA2, x3 = vA3;
      const f32x4  hv = hvA;
      if (d0 + 2 < 64) {
        const int Tn = (d0 + 2) * 4;
        bA0 = WpV[(Tn + 0) * 64 + l];  vA0 = bp[(Tn + 0) * 16 + c];
        bA1 = WpV[(Tn + 1) * 64 + l];  vA1 = bp[(Tn + 1) * 16 + c];
        bA2 = WpV[(Tn + 2) * 64 + l];  vA2 = bp[(Tn + 2) * 16 + c];
        bA3 = WpV[(Tn + 3) * 64 + l];  vA3 = bp[(Tn + 3) * 16 + c];
        hvA = *(const f32x4*)&hs[(d0 + 2) * EPF + hoff];
      }
      EDGE_SECTION(u0, u1, u2, u3, x0, x1, x2, x3, hv)
    }
    // ---- odd section: consume B set, prefetch B <- d0+3 ----
    {
      const bf16x8 u0 = bB0, u1 = bB1, u2 = bB2, u3 = bB3;
      const float  x0 = vB0, x1 = vB1, x2 = vB2, x3 = vB3;
      const f32x4  hv = hvB;
      if (d0 + 3 < 64) {
        const int Tn = (d0 + 3) * 4;
        bB0 = WpV[(Tn + 0) * 64 + l];  vB0 = bp[(Tn + 0) * 16 + c];
        bB1 = WpV[(Tn + 1) * 64 + l];  vB1 = bp[(Tn + 1) * 16 + c];
        bB2 = WpV[(Tn + 2) * 64 + l];  vB2 = bp[(Tn + 2) * 16 + c];
        bB3 = WpV[(Tn + 3) * 64 + l];  vB3 = bp[(Tn + 3) * 16 + c];
        hvB = *(const f32x4*)&hs[(d0 + 3) * EPF + hoff];
      }
      EDGE_SECTION(u0, u1, u2, u3, x0, x1, x2, x3, hv)
    }
  }
#undef EDGE_SECTION

  // stores: per (ht, row): 16 lanes x 4B = 64B segment; 16 stores/lane
  const int ebase = eblk + (w << 4) + (g << 2);
#pragma unroll
  for (int ht = 0; ht < 4; ++ht) {
    const int hcol = (ht << 4) + c;
    f32x2 a = accA[ht], b = accB[ht];
    m[((ebase + 0) << 6) + hcol] = a[0];
    m[((ebase + 1) << 6) + hcol] = a[1];
    m[((ebase + 2) << 6) + hcol] = b[0];
    m[((ebase + 3) << 6) + hcol] = b[1];
  }
}

// ---- final: gather-mean per dst (CSR) fused with out = relu(concat@Wn + bn) ----
// Block: 4 waves x 2 rows each = 8 rows; grid 1024. Wn in LDS (32 KB); 2-deep gather ILP.
__global__ __launch_bounds__(256) void final5_kernel(
    const float* __restrict__ nf, const float* __restrict__ m,
    const int* __restrict__ off, const int* __restrict__ eid,
    const float* __restrict__ Wn, const float* __restrict__ bn,
    float* __restrict__ out) {
  __shared__ float wn_s[128 * 64];   // 32 KB
  __shared__ float hn_s[8 * 64];     // 2 KB
  const int t = threadIdx.x;
#pragma unroll
  for (int i = 0; i < 8; ++i)
    ((f32x4*)wn_s)[i * 256 + t] = ((const f32x4*)Wn)[i * 256 + t];

  const int w = t >> 6, h = t & 63;
  const int row0 = blockIdx.x * 8 + w * 2;

#pragma unroll
  for (int i = 0; i < 2; ++i) {
    const int d = row0 + i;
    const int lo = off[d], hi = off[d + 1];
    float a0 = 0.f, a1 = 0.f;
    int j = lo;
    for (; j + 2 <= hi; j += 2) {
      const int e0 = eid[j], e1 = eid[j + 1];
      a0 += m[(e0 << 6) + h];
      a1 += m[(e1 << 6) + h];
    }
    if (j < hi) a0 += m[(eid[j] << 6) + h];
    const float a = a0 + a1;
    hn_s[(w * 2 + i) * 64 + h] = (hi > lo) ? a * (1.f / (float)(hi - lo)) : 0.f;
  }
  __syncthreads();

  const float bv = bn[h];
  float acc[2] = {bv, bv};
#pragma unroll 4
  for (int k = 0; k < 64; ++k) {
    const float wv = wn_s[k * 64 + h];
#pragma unroll
    for (int i = 0; i < 2; ++i)
      acc[i] = fmaf(nf[(row0 + i) * 64 + k], wv, acc[i]);
  }
#pragma unroll 4
  for (int k = 0; k < 64; ++k) {
    const float wv = wn_s[(64 + k) * 64 + h];
#pragma unroll
    for (int i = 0; i < 2; ++i)
      acc[i] = fmaf(hn_s[(w * 2 + i) * 64 + k], wv, acc[i]);
  }
#pragma unroll
  for (int i = 0; i < 2; ++i)
    out[(row0 + i) * 64 + h] = fmaxf(acc[i], 0.f);
}

// ================= atomic fallback (R3, proven) =================

__global__ __launch_bounds__(256, 4) void edge_kernel(
    const float* __restrict__ nf, const float* __restrict__ ef,
    const int* __restrict__ src, const int* __restrict__ dst,
    const __bf16* __restrict__ Wp, const float* __restrict__ bp,
    float* __restrict__ msum, float* __restrict__ cnt_g) {
  __shared__ __bf16 hs[64 * EPW];
  const int t = threadIdx.x;
  const int eblk = blockIdx.x << 6;
  {
    const int el = t & 63, q = t >> 6;
    const int srow = src[eblk + el];
    const f32x4* nfr = (const f32x4*)(nf + (srow << 6) + (q << 4));
#pragma unroll
    for (int i = 0; i < 4; ++i) {
      f32x4 v = nfr[i];
      const int dbase = (q << 4) + i * 4;
      hs[(dbase + 0) * EPW + el] = (__bf16)v[0];
      hs[(dbase + 1) * EPW + el] = (__bf16)v[1];
      hs[(dbase + 2) * EPW + el] = (__bf16)v[2];
      hs[(dbase + 3) * EPW + el] = (__bf16)v[3];
    }
  }
  const int w = t >> 6, l = t & 63, c = l & 15, g = l >> 4;
  bf16x8 afr[4];
#pragma unroll
  for (int as = 0; as < 4; ++as) {
    const int e = eblk + as * 16 + c;
    const f32x4* p = (const f32x4*)(ef + (e << 5) + (g << 3));
    f32x4 v0 = p[0], v1 = p[1];
    bf16x8 a;
    a[0] = (__bf16)v0[0]; a[1] = (__bf16)v0[1]; a[2] = (__bf16)v0[2]; a[3] = (__bf16)v0[3];
    a[4] = (__bf16)v1[0]; a[5] = (__bf16)v1[1]; a[6] = (__bf16)v1[2]; a[7] = (__bf16)v1[3];
    afr[as] = a;
  }
  __syncthreads();
  f32x4 acc[4];
#pragma unroll
  for (int i = 0; i < 4; ++i) { acc[i][0]=0.f; acc[i][1]=0.f; acc[i][2]=0.f; acc[i][3]=0.f; }
  const bf16x8* WpV = (const bf16x8*)Wp;
  const f32x4 zero = {0.f, 0.f, 0.f, 0.f};
#pragma unroll 4
  for (int d0 = 0; d0 < 64; ++d0) {
    const int T = d0 * 4 + w;
    const bf16x8 bfr = WpV[T * 64 + l];
    const float bv = bp[T * 16 + c];
    const f32x4 cb = {bv, bv, bv, bv};
#pragma unroll
    for (int as = 0; as < 4; ++as) {
      const bf16x4 hv = *(const bf16x4*)&hs[d0 * EPW + as * 16 + (g << 2)];
      const f32x4 hvf = {(float)hv[0], (float)hv[1], (float)hv[2], (float)hv[3]};
      f32x4 tmp = __builtin_amdgcn_mfma_f32_16x16x32_bf16(afr[as], bfr, cb, 0, 0, 0);
      tmp = __builtin_elementwise_max(tmp, zero);
      acc[as] = tmp * hvf + acc[as];
    }
  }
#pragma unroll
  for (int as = 0; as < 4; ++as)
#pragma unroll
    for (int r = 0; r < 4; ++r) {
      const int e = eblk + as * 16 + (g << 2) + r;
      const int dd = dst[e];
      unsafeAtomicAdd(msum + (dd << 6) + (w << 4) + c, acc[as][r]);
      if (w == 0 && c == 0) unsafeAtomicAdd(cnt_g + dd, 1.0f);
    }
}

__global__ __launch_bounds__(256) void final_kernel(
    const float* __restrict__ nf, const float* __restrict__ msum,
    const float* __restrict__ cnt, const float* __restrict__ Wn,
    const float* __restrict__ bn, float* __restrict__ out) {
  __shared__ float wn_s[128 * 64];
  const int t = threadIdx.x;
#pragma unroll
  for (int i = 0; i < 8; ++i)
    ((f32x4*)wn_s)[i * 256 + t] = ((const f32x4*)Wn)[i * 256 + t];
  __syncthreads();
  const int w = t >> 6, h = t & 63;
  const int row0 = blockIdx.x * 16 + w * 4;
  const float bv = bn[h];
  float acc[4] = {bv, bv, bv, bv};
  float s[4];
#pragma unroll
  for (int i = 0; i < 4; ++i) {
    const float cv = cnt[row0 + i];
    s[i] = cv > 0.f ? 1.f / cv : 0.f;
  }
#pragma unroll 4
  for (int k = 0; k < 64; ++k) {
    const float wv = wn_s[k * 64 + h];
#pragma unroll
    for (int i = 0; i < 4; ++i) acc[i] = fmaf(nf[(row0 + i) * 64 + k], wv, acc[i]);
  }
#pragma unroll 4
  for (int k = 0; k < 64; ++k) {
    const float wv = wn_s[(64 + k) * 64 + h];
#pragma unroll
    for (int i = 0; i < 4; ++i) acc[i] = fmaf(msum[(row0 + i) * 64 + k] * s[i], wv, acc[i]);
  }
#pragma unroll
  for (int i = 0; i < 4; ++i) out[(row0 + i) * 64 + h] = fmaxf(acc[i], 0.f);
}

// ================= launcher =================

extern "C" void kernel_launch(void* const* d_in, const int* in_sizes, int n_in,
                              void* d_out, int out_size, void* d_ws, size_t ws_size,
                              hipStream_t stream) {
  const float* nf  = (const float*)d_in[0];
  const float* ef  = (const float*)d_in[1];
  const int*   src = (const int*)d_in[2];
  const int*   dst = (const int*)d_in[3];
  const float* We  = (const float*)d_in[4];
  const float* be  = (const float*)d_in[5];
  const float* Wn  = (const float*)d_in[6];
  const float* bn  = (const float*)d_in[7];
  float* out = (float*)d_out;
  char* ws = (char*)d_ws;

  const size_t MB = 16777216;  // m buffer bytes (E*64*4)
  const size_t T_OFF    = MB;
  const size_t T_CURSOR = T_OFF + 36864;
  const size_t T_CNTI   = T_CURSOR + 32768;
  const size_t T_EID    = T_CNTI + 32768;
  const size_t T_WP     = T_EID + 262144;
  const size_t T_BP     = T_WP + 262144;
  const size_t NEED     = T_BP + 16384;      // ~17.4 MB

  if (ws_size >= NEED) {
    float*  m      = (float*)ws;
    int*    off    = (int*)(ws + T_OFF);
    int*    cursor = (int*)(ws + T_CURSOR);
    int*    cnt_i  = (int*)(ws + T_CNTI);
    int*    eid    = (int*)(ws + T_EID);
    __bf16* Wp     = (__bf16*)(ws + T_WP);
    float*  bp     = (float*)(ws + T_BP);

    hipMemsetAsync(cnt_i, 0, 32768, stream);
    prep_kernel<<<64, 256, 0, stream>>>(We, be, Wp, bp);
    edge6_kernel<<<E_TOT / 64, 256, 0, stream>>>(nf, ef, src, dst, Wp, bp, m, cnt_i);
    scan_kernel<<<1, 256, 0, stream>>>(cnt_i, off, cursor);
    fill_kernel<<<E_TOT / 256, 256, 0, stream>>>(dst, cursor, eid);
    final5_kernel<<<NDST / 8, 256, 0, stream>>>(nf, m, off, eid, Wn, bn, out);
  } else {
    // atomic fallback
    float* msum = (float*)ws;
    float* cnt  = (float*)(ws + 2097152);
    const size_t need = 2097152 + 32768 + 262144 + 16384;
    __bf16* Wp;
    float*  bp;
    if (ws_size >= need) {
      Wp = (__bf16*)(ws + 2097152 + 32768);
      bp = (float*)(ws + 2097152 + 32768 + 262144);
    } else {
      Wp = (__bf16*)d_out;
      bp = (float*)((char*)d_out + 262144);
    }
    hipMemsetAsync(msum, 0, 2097152 + 32768, stream);
    prep_kernel<<<64, 256, 0, stream>>>(We, be, Wp, bp);
    edge_kernel<<<E_TOT / 64, 256, 0, stream>>>(nf, ef, src, dst, Wp, bp, msum, cnt);
    final_kernel<<<NDST / 16, 256, 0, stream>>>(nf, msum, cnt, Wn, bn, out);
  }
}

// Round 9
// 104.009 us; speedup vs baseline: 1.1310x; 1.1310x over previous
//
#include <hip/hip_runtime.h>

// ECConv: out = relu(concat(nf[:8192], mean_seg(relu(EF@We+be).reshape(E,64,64) @ h_src)) @ Wn + bn)
// Sizes: E=65536, N_SRC=32768, N_DST=8192, EDGE_IN=32, NODE_IN=64, HIDDEN=64
// R9: LDS-staged B-stream (canonical GEMM staging). Law from R4-R8: edge time ~ per-wave
//     hot-loop global-load count (48us @ 2 loads/d0, 89us @ 8 loads/d0), insensitive to
//     occupancy/VALU. Fix: zero global loads in hot loop — Wp+bias windows (4 d0 = 16KB)
//     double-buffered in LDS via T14 issue-early/write-late reg staging; one barrier/window.
// Lessons: R2 fp32 atomics memory-side (~50-85G/s). R4 serial scan 20us. R5 forced VGPR=32
//     -> spills. R6 sequential dispatches don't stack. R8 per-wave load issue serializes.

typedef float f32x4 __attribute__((ext_vector_type(4)));
typedef float f32x2 __attribute__((ext_vector_type(2)));
typedef __bf16 bf16x8 __attribute__((ext_vector_type(8)));
typedef __bf16 bf16x4 __attribute__((ext_vector_type(4)));

#define E_TOT   65536
#define NDST    8192
#define EPW     72    // bf16 hs pad (atomic-fallback kernel)
#define EP2     136   // bf16 hs pad (edge7), 128 edges + 8

// ---- prep: pack We (fp32 [32][4096]) -> MFMA-B fragment order bf16 + bias tiles; zero cnt ----
// Tile T = d0*4 + ht covers GEMM cols n = (ht*16 + c)*64 + d0, c=0..15.
// B frag for mfma_f32_16x16x32_bf16: lane l holds B[k=(l>>4)*8+j][col=l&15], j=0..7.
__global__ __launch_bounds__(256) void prep_kernel(
    const float* __restrict__ We, const float* __restrict__ be,
    __bf16* __restrict__ Wp, float* __restrict__ bp, int* __restrict__ cnt_i) {
  int tid = blockIdx.x * 256 + threadIdx.x;       // 16384 packers
  if (tid < NDST) cnt_i[tid] = 0;                 // zero histogram (hist runs in edge dispatch)
  int T = tid >> 6, l = tid & 63;
  int d0 = T >> 2, ht = T & 3;
  int c = l & 15, kg = l >> 4;
  int ncol = (ht * 16 + c) * 64 + d0;
  bf16x8 v;
#pragma unroll
  for (int j = 0; j < 8; ++j) v[j] = (__bf16)We[(kg * 8 + j) * 4096 + ncol];
  *reinterpret_cast<bf16x8*>(Wp + tid * 8) = v;
  if (l < 16) bp[T * 16 + l] = be[(ht * 16 + l) * 64 + d0];
}

// ---- parallel exclusive scan over 8192 bins (one block, shfl + LDS) ----
__global__ __launch_bounds__(256) void scan_kernel(const int* __restrict__ cnt_i,
                                                   int* __restrict__ off,
                                                   int* __restrict__ cursor) {
  __shared__ int wsum[4];
  const int t = threadIdx.x;           // each thread owns 32 consecutive bins
  const int lane = t & 63, w = t >> 6;
  int vals[32];
  const int4* cp = (const int4*)(cnt_i + t * 32);
#pragma unroll
  for (int i = 0; i < 8; ++i) {
    int4 v = cp[i];
    vals[i * 4 + 0] = v.x; vals[i * 4 + 1] = v.y;
    vals[i * 4 + 2] = v.z; vals[i * 4 + 3] = v.w;
  }
  int loc[32];
  int s = 0;
#pragma unroll
  for (int i = 0; i < 32; ++i) { loc[i] = s; s += vals[i]; }
  int inc = s;
#pragma unroll
  for (int d = 1; d < 64; d <<= 1) {
    int n = __shfl_up(inc, d, 64);
    if (lane >= d) inc += n;
  }
  if (lane == 63) wsum[w] = inc;
  __syncthreads();
  int base = inc - s;
#pragma unroll
  for (int i = 0; i < 4; ++i)
    if (i < w) base += wsum[i];
#pragma unroll
  for (int i = 0; i < 32; ++i) {
    int v = base + loc[i];
    off[t * 32 + i] = v;
    cursor[t * 32 + i] = v;
  }
  if (t == 255) off[8192] = E_TOT;
}

// ---- fill: scatter edge ids into CSR order (int atomics on cursor) ----
__global__ void fill_kernel(const int* __restrict__ dst, int* __restrict__ cursor,
                            int* __restrict__ eid) {
  int e = blockIdx.x * 256 + threadIdx.x;
  int slot = atomicAdd(&cursor[dst[e]], 1);
  eid[slot] = e;
}

// ---- edge compute: m[e][h] = sum_d relu(ef[e]@We[:,h,d] + be[h,d]) * h_src[e][d] ----
// Block: 4 waves, 128 edges; wave w owns edges [w*32, w*32+32) = 2 A-frags (regs).
// Hot loop has ZERO global loads: Wp/bias staged per 4-d0 window (16KB) into LDS dbuf;
// T14 issue-early/write-late staging; one barrier per window. hs (h_src^T) bf16 in LDS.
__global__ __launch_bounds__(256, 2) void edge7_kernel(
    const float* __restrict__ nf, const float* __restrict__ ef,
    const int* __restrict__ src, const int* __restrict__ dst,
    const __bf16* __restrict__ Wp, const float* __restrict__ bp,
    float* __restrict__ m, int* __restrict__ cnt_i) {
  __shared__ __align__(16) __bf16 hs[64 * EP2];   // 17408 B : hs[d][e_local]
  __shared__ uint4 wp_s[2][1024];                 // 2 x 16KB : 16 tiles x 64 lanes x 16B
  __shared__ float bias_s[2][256];                // 2 x 1KB  : [dl][c][ht] permuted
  const int t = threadIdx.x;
  const int eblk = blockIdx.x << 7;               // 128 edges per block

  // stage h_src transposed (bf16): thread t -> edge el=t&127, d-half q=t>>7 (32 d each)
  {
    const int el = t & 127, q = t >> 7;
    const int srow = src[eblk + el];
    const f32x4* nfr = (const f32x4*)(nf + (srow << 6) + (q << 5));
#pragma unroll
    for (int i = 0; i < 8; ++i) {
      f32x4 v = nfr[i];
      const int d = (q << 5) + (i << 2);
      hs[(d + 0) * EP2 + el] = (__bf16)v[0];
      hs[(d + 1) * EP2 + el] = (__bf16)v[1];
      hs[(d + 2) * EP2 + el] = (__bf16)v[2];
      hs[(d + 3) * EP2 + el] = (__bf16)v[3];
    }
  }

  // fused dst histogram (cnt_i zeroed by prep)
  if (t < 128) atomicAdd(&cnt_i[dst[eblk + t]], 1);

  const int w = t >> 6, l = t & 63;
  const int c = l & 15, g = l >> 4;
  const uint4* WpQ = (const uint4*)Wp;
  // bias permute position: t = (dl*4+ht)*16+c  ->  [dl][c][ht]
  const int bpos = (((t >> 6) * 16) + (t & 15)) * 4 + ((t >> 4) & 3);

  // A fragments (regs, whole kernel): lane holds A[row=c][k=g*8+j]; as=0/1 -> afrA/afrB
  bf16x8 afrA, afrB;
  {
    const int e0 = eblk + (w << 5) + c;
    const f32x4* p0 = (const f32x4*)(ef + (e0 << 5) + (g << 3));
    f32x4 v0 = p0[0], v1 = p0[1];
    afrA[0] = (__bf16)v0[0]; afrA[1] = (__bf16)v0[1]; afrA[2] = (__bf16)v0[2]; afrA[3] = (__bf16)v0[3];
    afrA[4] = (__bf16)v1[0]; afrA[5] = (__bf16)v1[1]; afrA[6] = (__bf16)v1[2]; afrA[7] = (__bf16)v1[3];
    const f32x4* p1 = (const f32x4*)(ef + ((e0 + 16) << 5) + (g << 3));
    f32x4 u0 = p1[0], u1 = p1[1];
    afrB[0] = (__bf16)u0[0]; afrB[1] = (__bf16)u0[1]; afrB[2] = (__bf16)u0[2]; afrB[3] = (__bf16)u0[3];
    afrB[4] = (__bf16)u1[0]; afrB[5] = (__bf16)u1[1]; afrB[6] = (__bf16)u1[2]; afrB[7] = (__bf16)u1[3];
  }

  // stage window 0 (tiles 0..15) into buf 0
  {
    uint4 s0 = WpQ[t], s1 = WpQ[256 + t], s2 = WpQ[512 + t], s3 = WpQ[768 + t];
    float sb = bp[t];
    wp_s[0][t] = s0; wp_s[0][256 + t] = s1; wp_s[0][512 + t] = s2; wp_s[0][768 + t] = s3;
    bias_s[0][bpos] = sb;
  }

  f32x4 accA[4], accB[4];   // [ht]; rows g*4+0..3 for as=0 / as=1
#pragma unroll
  for (int i = 0; i < 4; ++i) {
    accA[i][0]=0.f; accA[i][1]=0.f; accA[i][2]=0.f; accA[i][3]=0.f;
    accB[i][0]=0.f; accB[i][1]=0.f; accB[i][2]=0.f; accB[i][3]=0.f;
  }

  __syncthreads();

  const int hoffA = (w << 5) + (g << 2);        // hs col base, as=0
  int cur = 0;

  for (int win = 0; win < 16; ++win) {
    // T14 issue-early: loads for window win+1
    uint4 s0, s1, s2, s3; float sb;
    const bool pf = (win < 15);
    if (pf) {
      const int base = (win + 1) << 10;
      s0 = WpQ[base + t]; s1 = WpQ[base + 256 + t];
      s2 = WpQ[base + 512 + t]; s3 = WpQ[base + 768 + t];
      sb = bp[((win + 1) << 8) + t];
    }

    // compute 4 d0 on buf[cur]
    const bf16x8* wpf = (const bf16x8*)&wp_s[cur][0];
    const float*  bsf = &bias_s[cur][0];
#pragma unroll
    for (int dl = 0; dl < 4; ++dl) {
      const int d0 = (win << 2) + dl;
      const bf16x8 wf0 = wpf[(dl * 4 + 0) * 64 + l];
      const bf16x8 wf1 = wpf[(dl * 4 + 1) * 64 + l];
      const bf16x8 wf2 = wpf[(dl * 4 + 2) * 64 + l];
      const bf16x8 wf3 = wpf[(dl * 4 + 3) * 64 + l];
      const f32x4  bv4 = *(const f32x4*)&bsf[(dl * 16 + c) * 4];
      const bf16x4 hva = *(const bf16x4*)&hs[d0 * EP2 + hoffA];
      const bf16x4 hvb = *(const bf16x4*)&hs[d0 * EP2 + hoffA + 16];
      const f32x4 ha = {(float)hva[0], (float)hva[1], (float)hva[2], (float)hva[3]};
      const f32x4 hb = {(float)hvb[0], (float)hvb[1], (float)hvb[2], (float)hvb[3]};
      const f32x4 zero = {0.f, 0.f, 0.f, 0.f};
#define DO_HT(HT, WF)                                                                 \
      {                                                                               \
        const f32x4 cb = {bv4[HT], bv4[HT], bv4[HT], bv4[HT]};                        \
        f32x4 ta = __builtin_amdgcn_mfma_f32_16x16x32_bf16(afrA, WF, cb, 0, 0, 0);    \
        ta = __builtin_elementwise_max(ta, zero);                                     \
        accA[HT] = ta * ha + accA[HT];                                                \
        f32x4 tb = __builtin_amdgcn_mfma_f32_16x16x32_bf16(afrB, WF, cb, 0, 0, 0);    \
        tb = __builtin_elementwise_max(tb, zero);                                     \
        accB[HT] = tb * hb + accB[HT];                                                \
      }
      DO_HT(0, wf0) DO_HT(1, wf1) DO_HT(2, wf2) DO_HT(3, wf3)
#undef DO_HT
    }

    // T14 write-late: commit window win+1 into the other buffer, then barrier
    if (pf) {
      const int nb = cur ^ 1;
      wp_s[nb][t] = s0; wp_s[nb][256 + t] = s1;
      wp_s[nb][512 + t] = s2; wp_s[nb][768 + t] = s3;
      bias_s[nb][bpos] = sb;
    }
    __syncthreads();
    cur ^= 1;
  }

  // stores: per (ht,row): 16 lanes x 4B = 64B segments
  const int e0 = eblk + (w << 5) + (g << 2);
#pragma unroll
  for (int ht = 0; ht < 4; ++ht) {
    const int col = (ht << 4) + c;
    m[((e0 + 0) << 6) + col] = accA[ht][0];
    m[((e0 + 1) << 6) + col] = accA[ht][1];
    m[((e0 + 2) << 6) + col] = accA[ht][2];
    m[((e0 + 3) << 6) + col] = accA[ht][3];
    m[((e0 + 16) << 6) + col] = accB[ht][0];
    m[((e0 + 17) << 6) + col] = accB[ht][1];
    m[((e0 + 18) << 6) + col] = accB[ht][2];
    m[((e0 + 19) << 6) + col] = accB[ht][3];
  }
}

// ---- final: gather-mean per dst (CSR) fused with out = relu(concat@Wn + bn) ----
// Block: 4 waves x 2 rows each = 8 rows; grid 1024. Wn in LDS (32 KB); 2-deep gather ILP.
__global__ __launch_bounds__(256) void final5_kernel(
    const float* __restrict__ nf, const float* __restrict__ m,
    const int* __restrict__ off, const int* __restrict__ eid,
    const float* __restrict__ Wn, const float* __restrict__ bn,
    float* __restrict__ out) {
  __shared__ float wn_s[128 * 64];   // 32 KB
  __shared__ float hn_s[8 * 64];     // 2 KB
  const int t = threadIdx.x;
#pragma unroll
  for (int i = 0; i < 8; ++i)
    ((f32x4*)wn_s)[i * 256 + t] = ((const f32x4*)Wn)[i * 256 + t];

  const int w = t >> 6, h = t & 63;
  const int row0 = blockIdx.x * 8 + w * 2;

#pragma unroll
  for (int i = 0; i < 2; ++i) {
    const int d = row0 + i;
    const int lo = off[d], hi = off[d + 1];
    float a0 = 0.f, a1 = 0.f;
    int j = lo;
    for (; j + 2 <= hi; j += 2) {
      const int e0 = eid[j], e1 = eid[j + 1];
      a0 += m[(e0 << 6) + h];
      a1 += m[(e1 << 6) + h];
    }
    if (j < hi) a0 += m[(eid[j] << 6) + h];
    const float a = a0 + a1;
    hn_s[(w * 2 + i) * 64 + h] = (hi > lo) ? a * (1.f / (float)(hi - lo)) : 0.f;
  }
  __syncthreads();

  const float bv = bn[h];
  float acc[2] = {bv, bv};
#pragma unroll 4
  for (int k = 0; k < 64; ++k) {
    const float wv = wn_s[k * 64 + h];
#pragma unroll
    for (int i = 0; i < 2; ++i)
      acc[i] = fmaf(nf[(row0 + i) * 64 + k], wv, acc[i]);
  }
#pragma unroll 4
  for (int k = 0; k < 64; ++k) {
    const float wv = wn_s[(64 + k) * 64 + h];
#pragma unroll
    for (int i = 0; i < 2; ++i)
      acc[i] = fmaf(hn_s[(w * 2 + i) * 64 + k], wv, acc[i]);
  }
#pragma unroll
  for (int i = 0; i < 2; ++i)
    out[(row0 + i) * 64 + h] = fmaxf(acc[i], 0.f);
}

// ================= atomic fallback (R3, proven) =================

__global__ __launch_bounds__(256, 4) void edge_kernel(
    const float* __restrict__ nf, const float* __restrict__ ef,
    const int* __restrict__ src, const int* __restrict__ dst,
    const __bf16* __restrict__ Wp, const float* __restrict__ bp,
    float* __restrict__ msum, float* __restrict__ cnt_g) {
  __shared__ __bf16 hs[64 * EPW];
  const int t = threadIdx.x;
  const int eblk = blockIdx.x << 6;
  {
    const int el = t & 63, q = t >> 6;
    const int srow = src[eblk + el];
    const f32x4* nfr = (const f32x4*)(nf + (srow << 6) + (q << 4));
#pragma unroll
    for (int i = 0; i < 4; ++i) {
      f32x4 v = nfr[i];
      const int dbase = (q << 4) + i * 4;
      hs[(dbase + 0) * EPW + el] = (__bf16)v[0];
      hs[(dbase + 1) * EPW + el] = (__bf16)v[1];
      hs[(dbase + 2) * EPW + el] = (__bf16)v[2];
      hs[(dbase + 3) * EPW + el] = (__bf16)v[3];
    }
  }
  const int w = t >> 6, l = t & 63, c = l & 15, g = l >> 4;
  bf16x8 afr[4];
#pragma unroll
  for (int as = 0; as < 4; ++as) {
    const int e = eblk + as * 16 + c;
    const f32x4* p = (const f32x4*)(ef + (e << 5) + (g << 3));
    f32x4 v0 = p[0], v1 = p[1];
    bf16x8 a;
    a[0] = (__bf16)v0[0]; a[1] = (__bf16)v0[1]; a[2] = (__bf16)v0[2]; a[3] = (__bf16)v0[3];
    a[4] = (__bf16)v1[0]; a[5] = (__bf16)v1[1]; a[6] = (__bf16)v1[2]; a[7] = (__bf16)v1[3];
    afr[as] = a;
  }
  __syncthreads();
  f32x4 acc[4];
#pragma unroll
  for (int i = 0; i < 4; ++i) { acc[i][0]=0.f; acc[i][1]=0.f; acc[i][2]=0.f; acc[i][3]=0.f; }
  const bf16x8* WpV = (const bf16x8*)Wp;
  const f32x4 zero = {0.f, 0.f, 0.f, 0.f};
#pragma unroll 4
  for (int d0 = 0; d0 < 64; ++d0) {
    const int T = d0 * 4 + w;
    const bf16x8 bfr = WpV[T * 64 + l];
    const float bv = bp[T * 16 + c];
    const f32x4 cb = {bv, bv, bv, bv};
#pragma unroll
    for (int as = 0; as < 4; ++as) {
      const bf16x4 hv = *(const bf16x4*)&hs[d0 * EPW + as * 16 + (g << 2)];
      const f32x4 hvf = {(float)hv[0], (float)hv[1], (float)hv[2], (float)hv[3]};
      f32x4 tmp = __builtin_amdgcn_mfma_f32_16x16x32_bf16(afr[as], bfr, cb, 0, 0, 0);
      tmp = __builtin_elementwise_max(tmp, zero);
      acc[as] = tmp * hvf + acc[as];
    }
  }
#pragma unroll
  for (int as = 0; as < 4; ++as)
#pragma unroll
    for (int r = 0; r < 4; ++r) {
      const int e = eblk + as * 16 + (g << 2) + r;
      const int dd = dst[e];
      unsafeAtomicAdd(msum + (dd << 6) + (w << 4) + c, acc[as][r]);
      if (w == 0 && c == 0) unsafeAtomicAdd(cnt_g + dd, 1.0f);
    }
}

__global__ __launch_bounds__(256) void final_kernel(
    const float* __restrict__ nf, const float* __restrict__ msum,
    const float* __restrict__ cnt, const float* __restrict__ Wn,
    const float* __restrict__ bn, float* __restrict__ out) {
  __shared__ float wn_s[128 * 64];
  const int t = threadIdx.x;
#pragma unroll
  for (int i = 0; i < 8; ++i)
    ((f32x4*)wn_s)[i * 256 + t] = ((const f32x4*)Wn)[i * 256 + t];
  __syncthreads();
  const int w = t >> 6, h = t & 63;
  const int row0 = blockIdx.x * 16 + w * 4;
  const float bv = bn[h];
  float acc[4] = {bv, bv, bv, bv};
  float s[4];
#pragma unroll
  for (int i = 0; i < 4; ++i) {
    const float cv = cnt[row0 + i];
    s[i] = cv > 0.f ? 1.f / cv : 0.f;
  }
#pragma unroll 4
  for (int k = 0; k < 64; ++k) {
    const float wv = wn_s[k * 64 + h];
#pragma unroll
    for (int i = 0; i < 4; ++i) acc[i] = fmaf(nf[(row0 + i) * 64 + k], wv, acc[i]);
  }
#pragma unroll 4
  for (int k = 0; k < 64; ++k) {
    const float wv = wn_s[(64 + k) * 64 + h];
#pragma unroll
    for (int i = 0; i < 4; ++i) acc[i] = fmaf(msum[(row0 + i) * 64 + k] * s[i], wv, acc[i]);
  }
#pragma unroll
  for (int i = 0; i < 4; ++i) out[(row0 + i) * 64 + h] = fmaxf(acc[i], 0.f);
}

// ================= launcher =================

extern "C" void kernel_launch(void* const* d_in, const int* in_sizes, int n_in,
                              void* d_out, int out_size, void* d_ws, size_t ws_size,
                              hipStream_t stream) {
  const float* nf  = (const float*)d_in[0];
  const float* ef  = (const float*)d_in[1];
  const int*   src = (const int*)d_in[2];
  const int*   dst = (const int*)d_in[3];
  const float* We  = (const float*)d_in[4];
  const float* be  = (const float*)d_in[5];
  const float* Wn  = (const float*)d_in[6];
  const float* bn  = (const float*)d_in[7];
  float* out = (float*)d_out;
  char* ws = (char*)d_ws;

  const size_t MB = 16777216;  // m buffer bytes (E*64*4)
  const size_t T_OFF    = MB;
  const size_t T_CURSOR = T_OFF + 36864;
  const size_t T_CNTI   = T_CURSOR + 32768;
  const size_t T_EID    = T_CNTI + 32768;
  const size_t T_WP     = T_EID + 262144;
  const size_t T_BP     = T_WP + 262144;
  const size_t NEED     = T_BP + 16384;      // ~17.4 MB

  if (ws_size >= NEED) {
    float*  m      = (float*)ws;
    int*    off    = (int*)(ws + T_OFF);
    int*    cursor = (int*)(ws + T_CURSOR);
    int*    cnt_i  = (int*)(ws + T_CNTI);
    int*    eid    = (int*)(ws + T_EID);
    __bf16* Wp     = (__bf16*)(ws + T_WP);
    float*  bp     = (float*)(ws + T_BP);

    prep_kernel<<<64, 256, 0, stream>>>(We, be, Wp, bp, cnt_i);
    edge7_kernel<<<E_TOT / 128, 256, 0, stream>>>(nf, ef, src, dst, Wp, bp, m, cnt_i);
    scan_kernel<<<1, 256, 0, stream>>>(cnt_i, off, cursor);
    fill_kernel<<<E_TOT / 256, 256, 0, stream>>>(dst, cursor, eid);
    final5_kernel<<<NDST / 8, 256, 0, stream>>>(nf, m, off, eid, Wn, bn, out);
  } else {
    // atomic fallback
    float* msum = (float*)ws;
    float* cnt  = (float*)(ws + 2097152);
    const size_t need = 2097152 + 32768 + 262144 + 16384;
    __bf16* Wp;
    float*  bp;
    if (ws_size >= need) {
      Wp = (__bf16*)(ws + 2097152 + 32768);
      bp = (float*)(ws + 2097152 + 32768 + 262144);
    } else {
      Wp = (__bf16*)d_out;
      bp = (float*)((char*)d_out + 262144);
    }
    hipMemsetAsync(msum, 0, 2097152 + 32768, stream);
    prep_kernel<<<64, 256, 0, stream>>>(We, be, Wp, bp, (int*)cnt);
    edge_kernel<<<E_TOT / 64, 256, 0, stream>>>(nf, ef, src, dst, Wp, bp, msum, cnt);
    final_kernel<<<NDST / 16, 256, 0, stream>>>(nf, msum, cnt, Wn, bn, out);
  }
}

// Round 10
// 81.823 us; speedup vs baseline: 1.4377x; 1.2712x over previous
//
#include <hip/hip_runtime.h>

// ECConv: out = relu(concat(nf[:8192], mean_seg(relu(EF@We+be).reshape(E,64,64) @ h_src)) @ Wn + bn)
// Sizes: E=65536, N_SRC=32768, N_DST=8192, EDGE_IN=32, NODE_IN=64, HIDDEN=64
// R10: R7 structure + zero hot-loop global loads. B/bias from single-buffered 8-d0 LDS window
//      (32KB+2KB) staged via global_load_lds (no reg liveness -> no spill; __has_builtin
//      fallback to immediate load->ds_write). Tests the R1-R8 law: time tracks hot-loop
//      per-wave global loads (2/iter -> 48us, 8/iter -> 89us); this kernel has 0/iter.
// Lessons: R2 fp32 atomics memory-side. R4 serial scan 20us. R5/R9 long-lived staging regs
//      -> spills (WRITE 5x payload is the tell). R6 sequential dispatches don't stack.
//      R6/R7 occupancy 22-45% identical -> not TLP-limited.

typedef float f32x4 __attribute__((ext_vector_type(4)));
typedef float f32x2 __attribute__((ext_vector_type(2)));
typedef __bf16 bf16x8 __attribute__((ext_vector_type(8)));
typedef __bf16 bf16x4 __attribute__((ext_vector_type(4)));

#define E_TOT   65536
#define NDST    8192
#define EPW     72    // bf16 hs pad (atomic-fallback kernel)
#define EPF     68    // f32 hs pad (fast kernel)

#if defined(__has_builtin)
#if __has_builtin(__builtin_amdgcn_global_load_lds)
#define HAVE_GLL 1
#endif
#endif

// ---- prep: pack We -> MFMA-B fragment order bf16 + bias tiles; zero cnt ----
// Tile T = d0*4 + ht covers GEMM cols n = (ht*16 + c)*64 + d0, c=0..15.
// B frag for mfma_f32_16x16x32_bf16: lane l holds B[k=(l>>4)*8+j][col=l&15], j=0..7.
__global__ __launch_bounds__(256) void prep_kernel(
    const float* __restrict__ We, const float* __restrict__ be,
    __bf16* __restrict__ Wp, float* __restrict__ bp, int* __restrict__ cnt_i) {
  int tid = blockIdx.x * 256 + threadIdx.x;       // 16384 packers
  if (tid < NDST) cnt_i[tid] = 0;
  int T = tid >> 6, l = tid & 63;
  int d0 = T >> 2, ht = T & 3;
  int c = l & 15, kg = l >> 4;
  int ncol = (ht * 16 + c) * 64 + d0;
  bf16x8 v;
#pragma unroll
  for (int j = 0; j < 8; ++j) v[j] = (__bf16)We[(kg * 8 + j) * 4096 + ncol];
  *reinterpret_cast<bf16x8*>(Wp + tid * 8) = v;
  if (l < 16) bp[T * 16 + l] = be[(ht * 16 + l) * 64 + d0];
}

// ---- parallel exclusive scan over 8192 bins (one block, shfl + LDS) ----
__global__ __launch_bounds__(256) void scan_kernel(const int* __restrict__ cnt_i,
                                                   int* __restrict__ off,
                                                   int* __restrict__ cursor) {
  __shared__ int wsum[4];
  const int t = threadIdx.x;
  const int lane = t & 63, w = t >> 6;
  int vals[32];
  const int4* cp = (const int4*)(cnt_i + t * 32);
#pragma unroll
  for (int i = 0; i < 8; ++i) {
    int4 v = cp[i];
    vals[i * 4 + 0] = v.x; vals[i * 4 + 1] = v.y;
    vals[i * 4 + 2] = v.z; vals[i * 4 + 3] = v.w;
  }
  int loc[32];
  int s = 0;
#pragma unroll
  for (int i = 0; i < 32; ++i) { loc[i] = s; s += vals[i]; }
  int inc = s;
#pragma unroll
  for (int d = 1; d < 64; d <<= 1) {
    int n = __shfl_up(inc, d, 64);
    if (lane >= d) inc += n;
  }
  if (lane == 63) wsum[w] = inc;
  __syncthreads();
  int base = inc - s;
#pragma unroll
  for (int i = 0; i < 4; ++i)
    if (i < w) base += wsum[i];
#pragma unroll
  for (int i = 0; i < 32; ++i) {
    int v = base + loc[i];
    off[t * 32 + i] = v;
    cursor[t * 32 + i] = v;
  }
  if (t == 255) off[8192] = E_TOT;
}

// ---- fill: scatter edge ids into CSR order (int atomics on cursor) ----
__global__ void fill_kernel(const int* __restrict__ dst, int* __restrict__ cursor,
                            int* __restrict__ eid) {
  int e = blockIdx.x * 256 + threadIdx.x;
  int slot = atomicAdd(&cursor[dst[e]], 1);
  eid[slot] = e;
}

// ---- edge compute: m[e][h] = sum_d relu(ef[e]@We[:,h,d] + be[h,d]) * h_src[e][d] ----
// R7 shape: 4 waves, 64 edges; wave w owns h-quadrant ht=w, 4 A-frags; per d0: 1 B-frag +
// 1 bias + 4 MFMA + pk-fma epilogue. B/bias now read from an 8-d0 LDS window staged via
// global_load_lds (zero global loads in the hot loop). 16 barriers total. Hist fused.
__global__ __launch_bounds__(256, 2) void edge8_kernel(
    const float* __restrict__ nf, const float* __restrict__ ef,
    const int* __restrict__ src, const int* __restrict__ dst,
    const __bf16* __restrict__ Wp, const float* __restrict__ bp,
    float* __restrict__ m, int* __restrict__ cnt_i) {
  __shared__ __align__(16) float hs[64 * EPF];      // 17408 B : hs[d][e_local] f32
  __shared__ __align__(16) __bf16 wwin[16384];      // 32768 B : 8 d0 x 4 ht x 64 lanes x 8
  __shared__ __align__(16) float bwin[512];         // 2048 B  : 8 d0 x 4 ht x 16 c
  const int t = threadIdx.x;
  const int eblk = blockIdx.x << 6;

  // stage h_src transposed: thread t -> edge el=t&63, d-quarter q=t>>6 (16 d each)
  {
    const int el = t & 63, q = t >> 6;
    const int srow = src[eblk + el];
    const f32x4* nfr = (const f32x4*)(nf + (srow << 6) + (q << 4));
#pragma unroll
    for (int i = 0; i < 4; ++i) {
      f32x4 v = nfr[i];
      const int dbase = (q << 4) + i * 4;
      hs[(dbase + 0) * EPF + el] = v[0];
      hs[(dbase + 1) * EPF + el] = v[1];
      hs[(dbase + 2) * EPF + el] = v[2];
      hs[(dbase + 3) * EPF + el] = v[3];
    }
  }

  // fused dst histogram (cnt_i zeroed by prep)
  if (t < 64) atomicAdd(&cnt_i[dst[eblk + t]], 1);

  const int w = t >> 6, l = t & 63;
  const int c = l & 15, g = l >> 4;

  // A fragments (regs, whole kernel): lane holds A[row=c][k=g*8+j], 4 edge-groups
  bf16x8 afr[4];
#pragma unroll
  for (int as = 0; as < 4; ++as) {
    const int e = eblk + as * 16 + c;
    const f32x4* p = (const f32x4*)(ef + (e << 5) + (g << 3));
    f32x4 v0 = p[0], v1 = p[1];
    bf16x8 a;
    a[0] = (__bf16)v0[0]; a[1] = (__bf16)v0[1]; a[2] = (__bf16)v0[2]; a[3] = (__bf16)v0[3];
    a[4] = (__bf16)v1[0]; a[5] = (__bf16)v1[1]; a[6] = (__bf16)v1[2]; a[7] = (__bf16)v1[3];
    afr[as] = a;
  }

  f32x2 accA[4], accB[4];   // [as]; rows (g*4+0,g*4+1) / (g*4+2,g*4+3)
#pragma unroll
  for (int i = 0; i < 4; ++i) {
    accA[i][0] = 0.f; accA[i][1] = 0.f;
    accB[i][0] = 0.f; accB[i][1] = 0.f;
  }

  const bf16x8* wv = (const bf16x8*)wwin;

  for (int win = 0; win < 8; ++win) {
    // ---- stage window win: Wp 32KB (contiguous, tile-major) + bias 2KB ----
#ifdef HAVE_GLL
    {
      // dest: wave-uniform base + lane*16 (linear); src: per-lane global address
      const char* gbase = (const char*)Wp + ((size_t)win << 15) + ((size_t)w << 13) + ((size_t)l << 4);
      char* lbase = (char*)wwin + (w << 13);
#pragma unroll
      for (int it = 0; it < 8; ++it) {
        auto gp = (const __attribute__((address_space(1))) uint32_t*)(uintptr_t)(gbase + (it << 10));
        auto lp = (__attribute__((address_space(3))) uint32_t*)(uintptr_t)(lbase + (it << 10));
        __builtin_amdgcn_global_load_lds(gp, lp, 16, 0, 0);
      }
    }
#else
    {
      const uint4* gq = (const uint4*)((const char*)Wp + ((size_t)win << 15));
      uint4* lq = (uint4*)wwin;
#pragma unroll
      for (int it = 0; it < 8; ++it) lq[t + (it << 8)] = gq[t + (it << 8)];
    }
#endif
    bwin[t] = bp[(win << 9) + t];
    bwin[t + 256] = bp[(win << 9) + 256 + t];
    __syncthreads();   // window ready (drains global_load_lds via vmcnt before barrier)

    // ---- compute 8 d0 from LDS only ----
#pragma unroll
    for (int dl = 0; dl < 8; ++dl) {
      const int d0 = (win << 3) + dl;
      const bf16x8 bfr = wv[(dl * 4 + w) * 64 + l];
      const float bv = bwin[(dl * 4 + w) * 16 + c];
      const f32x4 cb = {bv, bv, bv, bv};
#pragma unroll
      for (int as = 0; as < 4; ++as) {
        const f32x4 hvf = *(const f32x4*)&hs[d0 * EPF + as * 16 + (g << 2)];
        f32x4 tmp = __builtin_amdgcn_mfma_f32_16x16x32_bf16(afr[as], bfr, cb, 0, 0, 0);
        f32x2 tl = {fmaxf(tmp[0], 0.f), fmaxf(tmp[1], 0.f)};
        f32x2 th = {fmaxf(tmp[2], 0.f), fmaxf(tmp[3], 0.f)};
        f32x2 hl = __builtin_shufflevector(hvf, hvf, 0, 1);
        f32x2 hh = __builtin_shufflevector(hvf, hvf, 2, 3);
        asm("v_pk_fma_f32 %0, %1, %2, %0" : "+v"(accA[as]) : "v"(tl), "v"(hl));
        asm("v_pk_fma_f32 %0, %1, %2, %0" : "+v"(accB[as]) : "v"(th), "v"(hh));
      }
    }
    __syncthreads();   // all waves done with window before overwrite
  }

  // stores: per (as,row): 16 lanes x 4B = 64B segments
  const int hbase = (w << 4) + c;
#pragma unroll
  for (int as = 0; as < 4; ++as) {
    const int ebase = eblk + as * 16 + (g << 2);
    m[((ebase + 0) << 6) + hbase] = accA[as][0];
    m[((ebase + 1) << 6) + hbase] = accA[as][1];
    m[((ebase + 2) << 6) + hbase] = accB[as][0];
    m[((ebase + 3) << 6) + hbase] = accB[as][1];
  }
}

// ---- final: gather-mean per dst (CSR) fused with out = relu(concat@Wn + bn) ----
__global__ __launch_bounds__(256) void final5_kernel(
    const float* __restrict__ nf, const float* __restrict__ m,
    const int* __restrict__ off, const int* __restrict__ eid,
    const float* __restrict__ Wn, const float* __restrict__ bn,
    float* __restrict__ out) {
  __shared__ float wn_s[128 * 64];   // 32 KB
  __shared__ float hn_s[8 * 64];     // 2 KB
  const int t = threadIdx.x;
#pragma unroll
  for (int i = 0; i < 8; ++i)
    ((f32x4*)wn_s)[i * 256 + t] = ((const f32x4*)Wn)[i * 256 + t];

  const int w = t >> 6, h = t & 63;
  const int row0 = blockIdx.x * 8 + w * 2;

#pragma unroll
  for (int i = 0; i < 2; ++i) {
    const int d = row0 + i;
    const int lo = off[d], hi = off[d + 1];
    float a0 = 0.f, a1 = 0.f;
    int j = lo;
    for (; j + 2 <= hi; j += 2) {
      const int e0 = eid[j], e1 = eid[j + 1];
      a0 += m[(e0 << 6) + h];
      a1 += m[(e1 << 6) + h];
    }
    if (j < hi) a0 += m[(eid[j] << 6) + h];
    const float a = a0 + a1;
    hn_s[(w * 2 + i) * 64 + h] = (hi > lo) ? a * (1.f / (float)(hi - lo)) : 0.f;
  }
  __syncthreads();

  const float bv = bn[h];
  float acc[2] = {bv, bv};
#pragma unroll 4
  for (int k = 0; k < 64; ++k) {
    const float wv = wn_s[k * 64 + h];
#pragma unroll
    for (int i = 0; i < 2; ++i)
      acc[i] = fmaf(nf[(row0 + i) * 64 + k], wv, acc[i]);
  }
#pragma unroll 4
  for (int k = 0; k < 64; ++k) {
    const float wv = wn_s[(64 + k) * 64 + h];
#pragma unroll
    for (int i = 0; i < 2; ++i)
      acc[i] = fmaf(hn_s[(w * 2 + i) * 64 + k], wv, acc[i]);
  }
#pragma unroll
  for (int i = 0; i < 2; ++i)
    out[(row0 + i) * 64 + h] = fmaxf(acc[i], 0.f);
}

// ================= atomic fallback (R3, proven) =================

__global__ __launch_bounds__(256, 4) void edge_kernel(
    const float* __restrict__ nf, const float* __restrict__ ef,
    const int* __restrict__ src, const int* __restrict__ dst,
    const __bf16* __restrict__ Wp, const float* __restrict__ bp,
    float* __restrict__ msum, float* __restrict__ cnt_g) {
  __shared__ __bf16 hs[64 * EPW];
  const int t = threadIdx.x;
  const int eblk = blockIdx.x << 6;
  {
    const int el = t & 63, q = t >> 6;
    const int srow = src[eblk + el];
    const f32x4* nfr = (const f32x4*)(nf + (srow << 6) + (q << 4));
#pragma unroll
    for (int i = 0; i < 4; ++i) {
      f32x4 v = nfr[i];
      const int dbase = (q << 4) + i * 4;
      hs[(dbase + 0) * EPW + el] = (__bf16)v[0];
      hs[(dbase + 1) * EPW + el] = (__bf16)v[1];
      hs[(dbase + 2) * EPW + el] = (__bf16)v[2];
      hs[(dbase + 3) * EPW + el] = (__bf16)v[3];
    }
  }
  const int w = t >> 6, l = t & 63, c = l & 15, g = l >> 4;
  bf16x8 afr[4];
#pragma unroll
  for (int as = 0; as < 4; ++as) {
    const int e = eblk + as * 16 + c;
    const f32x4* p = (const f32x4*)(ef + (e << 5) + (g << 3));
    f32x4 v0 = p[0], v1 = p[1];
    bf16x8 a;
    a[0] = (__bf16)v0[0]; a[1] = (__bf16)v0[1]; a[2] = (__bf16)v0[2]; a[3] = (__bf16)v0[3];
    a[4] = (__bf16)v1[0]; a[5] = (__bf16)v1[1]; a[6] = (__bf16)v1[2]; a[7] = (__bf16)v1[3];
    afr[as] = a;
  }
  __syncthreads();
  f32x4 acc[4];
#pragma unroll
  for (int i = 0; i < 4; ++i) { acc[i][0]=0.f; acc[i][1]=0.f; acc[i][2]=0.f; acc[i][3]=0.f; }
  const bf16x8* WpV = (const bf16x8*)Wp;
  const f32x4 zero = {0.f, 0.f, 0.f, 0.f};
#pragma unroll 4
  for (int d0 = 0; d0 < 64; ++d0) {
    const int T = d0 * 4 + w;
    const bf16x8 bfr = WpV[T * 64 + l];
    const float bv = bp[T * 16 + c];
    const f32x4 cb = {bv, bv, bv, bv};
#pragma unroll
    for (int as = 0; as < 4; ++as) {
      const bf16x4 hv = *(const bf16x4*)&hs[d0 * EPW + as * 16 + (g << 2)];
      const f32x4 hvf = {(float)hv[0], (float)hv[1], (float)hv[2], (float)hv[3]};
      f32x4 tmp = __builtin_amdgcn_mfma_f32_16x16x32_bf16(afr[as], bfr, cb, 0, 0, 0);
      tmp = __builtin_elementwise_max(tmp, zero);
      acc[as] = tmp * hvf + acc[as];
    }
  }
#pragma unroll
  for (int as = 0; as < 4; ++as)
#pragma unroll
    for (int r = 0; r < 4; ++r) {
      const int e = eblk + as * 16 + (g << 2) + r;
      const int dd = dst[e];
      unsafeAtomicAdd(msum + (dd << 6) + (w << 4) + c, acc[as][r]);
      if (w == 0 && c == 0) unsafeAtomicAdd(cnt_g + dd, 1.0f);
    }
}

__global__ __launch_bounds__(256) void final_kernel(
    const float* __restrict__ nf, const float* __restrict__ msum,
    const float* __restrict__ cnt, const float* __restrict__ Wn,
    const float* __restrict__ bn, float* __restrict__ out) {
  __shared__ float wn_s[128 * 64];
  const int t = threadIdx.x;
#pragma unroll
  for (int i = 0; i < 8; ++i)
    ((f32x4*)wn_s)[i * 256 + t] = ((const f32x4*)Wn)[i * 256 + t];
  __syncthreads();
  const int w = t >> 6, h = t & 63;
  const int row0 = blockIdx.x * 16 + w * 4;
  const float bv = bn[h];
  float acc[4] = {bv, bv, bv, bv};
  float s[4];
#pragma unroll
  for (int i = 0; i < 4; ++i) {
    const float cv = cnt[row0 + i];
    s[i] = cv > 0.f ? 1.f / cv : 0.f;
  }
#pragma unroll 4
  for (int k = 0; k < 64; ++k) {
    const float wv = wn_s[k * 64 + h];
#pragma unroll
    for (int i = 0; i < 4; ++i) acc[i] = fmaf(nf[(row0 + i) * 64 + k], wv, acc[i]);
  }
#pragma unroll 4
  for (int k = 0; k < 64; ++k) {
    const float wv = wn_s[(64 + k) * 64 + h];
#pragma unroll
    for (int i = 0; i < 4; ++i) acc[i] = fmaf(msum[(row0 + i) * 64 + k] * s[i], wv, acc[i]);
  }
#pragma unroll
  for (int i = 0; i < 4; ++i) out[(row0 + i) * 64 + h] = fmaxf(acc[i], 0.f);
}

// ================= launcher =================

extern "C" void kernel_launch(void* const* d_in, const int* in_sizes, int n_in,
                              void* d_out, int out_size, void* d_ws, size_t ws_size,
                              hipStream_t stream) {
  const float* nf  = (const float*)d_in[0];
  const float* ef  = (const float*)d_in[1];
  const int*   src = (const int*)d_in[2];
  const int*   dst = (const int*)d_in[3];
  const float* We  = (const float*)d_in[4];
  const float* be  = (const float*)d_in[5];
  const float* Wn  = (const float*)d_in[6];
  const float* bn  = (const float*)d_in[7];
  float* out = (float*)d_out;
  char* ws = (char*)d_ws;

  const size_t MB = 16777216;  // m buffer bytes (E*64*4)
  const size_t T_OFF    = MB;
  const size_t T_CURSOR = T_OFF + 36864;
  const size_t T_CNTI   = T_CURSOR + 32768;
  const size_t T_EID    = T_CNTI + 32768;
  const size_t T_WP     = T_EID + 262144;
  const size_t T_BP     = T_WP + 262144;
  const size_t NEED     = T_BP + 16384;      // ~17.4 MB

  if (ws_size >= NEED) {
    float*  m      = (float*)ws;
    int*    off    = (int*)(ws + T_OFF);
    int*    cursor = (int*)(ws + T_CURSOR);
    int*    cnt_i  = (int*)(ws + T_CNTI);
    int*    eid    = (int*)(ws + T_EID);
    __bf16* Wp     = (__bf16*)(ws + T_WP);
    float*  bp     = (float*)(ws + T_BP);

    prep_kernel<<<64, 256, 0, stream>>>(We, be, Wp, bp, cnt_i);
    edge8_kernel<<<E_TOT / 64, 256, 0, stream>>>(nf, ef, src, dst, Wp, bp, m, cnt_i);
    scan_kernel<<<1, 256, 0, stream>>>(cnt_i, off, cursor);
    fill_kernel<<<E_TOT / 256, 256, 0, stream>>>(dst, cursor, eid);
    final5_kernel<<<NDST / 8, 256, 0, stream>>>(nf, m, off, eid, Wn, bn, out);
  } else {
    // atomic fallback
    float* msum = (float*)ws;
    float* cnt  = (float*)(ws + 2097152);
    const size_t need = 2097152 + 32768 + 262144 + 16384;
    __bf16* Wp;
    float*  bp;
    if (ws_size >= need) {
      Wp = (__bf16*)(ws + 2097152 + 32768);
      bp = (float*)(ws + 2097152 + 32768 + 262144);
    } else {
      Wp = (__bf16*)d_out;
      bp = (float*)((char*)d_out + 262144);
    }
    hipMemsetAsync(msum, 0, 2097152 + 32768, stream);
    prep_kernel<<<64, 256, 0, stream>>>(We, be, Wp, bp, (int*)cnt);
    edge_kernel<<<E_TOT / 64, 256, 0, stream>>>(nf, ef, src, dst, Wp, bp, msum, cnt);
    final_kernel<<<NDST / 16, 256, 0, stream>>>(nf, msum, cnt, Wn, bn, out);
  }
}